// Round 3
// baseline (197.092 us; speedup 1.0000x reference)
//
#include <hip/hip_runtime.h>

#define M_TOT 32768   // B*T = 64*512
#define T_LEN 512
#define NIN   256
#define NH    1024
#define NOUT  256

typedef __attribute__((ext_vector_type(8))) short bf16x8;
typedef __attribute__((ext_vector_type(4))) float f32x4;
typedef unsigned short u16;

__device__ inline float bf2f(u16 u) {
  union { float f; unsigned int i; } v; v.i = ((unsigned int)u) << 16; return v.f;
}
__device__ inline u16 f2bf(float f) {
  union { float f; unsigned int i; } v; v.f = f;
  unsigned int r = v.i + 0x7FFFu + ((v.i >> 16) & 1u);
  return (u16)(r >> 16);
}

__device__ inline void gload_lds16(const void* g, void* l) {
  __builtin_amdgcn_global_load_lds(
      (const __attribute__((address_space(1))) void*)g,
      (__attribute__((address_space(3))) void*)l, 16, 0, 0);
}

// ---------------- prep: bf16 conversions, WiT transpose, Acat build, zero row ----------------
// INz layout: row 0 = zeros (256), row r>=1 = IN row r-1.  [32769][256] bf16
__global__ void prep(const float* __restrict__ inp, const float* __restrict__ Wi,
                     const float* __restrict__ Wih, const float* __restrict__ Whh,
                     const float* __restrict__ Wo,
                     u16* __restrict__ INz, u16* __restrict__ WiT,
                     u16* __restrict__ Acat, u16* __restrict__ Wib, u16* __restrict__ Wob) {
  const long nINz = 256L + (long)M_TOT * NIN;   // 8,388,864
  const long nWiT = 256L * NH;                  // 262,144
  const long nAc  = 2048L * NH;                 // 2,097,152
  const long nWi  = (long)NH * NIN;             // 262,144
  const long nWo  = (long)NOUT * NH;            // 262,144
  const long total = nINz + nWiT + nAc + nWi + nWo;
  for (long i = (long)blockIdx.x * blockDim.x + threadIdx.x; i < total;
       i += (long)gridDim.x * blockDim.x) {
    long j = i;
    if (j < nINz) { INz[j] = (j < 256) ? (u16)0 : f2bf(inp[j - 256]); continue; }
    j -= nINz;
    if (j < nWiT) {  // WiT[it][h] = Wi[h][it]
      long it = j >> 10, h = j & 1023;
      WiT[j] = f2bf(Wi[h * NIN + it]);
      continue;
    }
    j -= nWiT;
    if (j < nAc) {   // Acat = [W_ih ; 0.98*W_hh]  (2048 x 1024)
      long g = j >> 10, h = j & 1023;
      Acat[j] = (g < NH) ? f2bf(Wih[g * NH + h])
                         : f2bf(0.98f * Whh[(g - NH) * NH + h]);
      continue;
    }
    j -= nAc;
    if (j < nWi) { Wib[j] = f2bf(Wi[j]); continue; }
    j -= nWi;
    Wob[j] = f2bf(Wo[j]);
  }
}

// ---------------- biasvec: b1[g]=bih+bhh+W_ih.bi ; b2[g]=0.98*W_hh.bi ----------------
__global__ __launch_bounds__(256) void biasvec(const float* __restrict__ Wih,
                                               const float* __restrict__ Whh,
                                               const float* __restrict__ bi,
                                               const float* __restrict__ bih,
                                               const float* __restrict__ bhh,
                                               float* __restrict__ bias1,
                                               float* __restrict__ bias2) {
  __shared__ float s1[256], s2[256];
  const int g = blockIdx.x, tid = threadIdx.x;
  float a1 = 0.f, a2 = 0.f;
#pragma unroll
  for (int q = 0; q < 4; q++) {
    int h = tid + q * 256;
    float bv = bi[h];
    a1 += Wih[(size_t)g * NH + h] * bv;
    a2 += Whh[(size_t)g * NH + h] * bv;
  }
  s1[tid] = a1; s2[tid] = a2;
  __syncthreads();
  for (int off = 128; off > 0; off >>= 1) {
    if (tid < off) { s1[tid] += s1[tid + off]; s2[tid] += s2[tid + off]; }
    __syncthreads();
  }
  if (tid == 0) {
    bias1[g] = s1[0] + bih[g] + bhh[g];
    bias2[g] = 0.98f * s2[0];
  }
}

// ---------------- wab: Wab2 = [Wa | Wb] folded weights, M=2048,N=256,K=1024 ----------------
__global__ __launch_bounds__(256) void wab(const u16* __restrict__ Acat,
                                           const u16* __restrict__ WiT,
                                           u16* __restrict__ Wab2) {
  __shared__ __align__(16) u16 As[128 * 32];
  __shared__ __align__(16) u16 Bs[128 * 32];
  const int tid = threadIdx.x;
  const int r0 = blockIdx.x * 128, c0 = blockIdx.y * 128;
  const int lane = tid & 63, wave = tid >> 6;
  const int wm = wave >> 1, wn = wave & 1;
  const int lm = lane & 15, kq = lane >> 4;

  f32x4 acc[4][4] = {};
  for (int k0 = 0; k0 < NH; k0 += 32) {
#pragma unroll
    for (int rr = 0; rr < 2; rr++) {
      int c = tid + rr * 256;
      int row = c >> 2, col = (c & 3) * 8;
      gload_lds16(Acat + (size_t)(r0 + row) * NH + k0 + col, (char*)As + c * 16);
      gload_lds16(WiT + (size_t)(c0 + row) * NH + k0 + col, (char*)Bs + c * 16);
    }
    __syncthreads();
    bf16x8 a[4], b[4];
#pragma unroll
    for (int i = 0; i < 4; i++) {
      a[i] = *(const bf16x8*)&As[(wm * 64 + i * 16 + lm) * 32 + kq * 8];
      b[i] = *(const bf16x8*)&Bs[(wn * 64 + i * 16 + lm) * 32 + kq * 8];
    }
#pragma unroll
    for (int i = 0; i < 4; i++)
#pragma unroll
      for (int jn = 0; jn < 4; jn++)
        acc[i][jn] = __builtin_amdgcn_mfma_f32_16x16x32_bf16(a[i], b[jn], acc[i][jn], 0, 0, 0);
    __syncthreads();
  }
#pragma unroll
  for (int i = 0; i < 4; i++) {
    int grb = r0 + wm * 64 + i * 16 + kq * 4;
#pragma unroll
    for (int jn = 0; jn < 4; jn++) {
      int gc = c0 + wn * 64 + jn * 16 + lm;
#pragma unroll
      for (int j = 0; j < 4; j++) {
        int g = grb + j;
        size_t dst = (g < NH) ? ((size_t)g * 512 + gc)
                              : ((size_t)(g - NH) * 512 + 256 + gc);
        Wab2[dst] = f2bf(acc[i][jn][j]);
      }
    }
  }
}

// ---- fused2: accX = IN_t*Wi^T (K=256); accC = IN_t*Wa^T + IN_prev*Wb^T (K=512);
// ----         H = 0.98*(accX+bi) + 0.02*relu(accC + b1 [+ b2 if t!=0]) -> out0 f32
__global__ __launch_bounds__(256) void fused2(const u16* __restrict__ INz,
                                              const u16* __restrict__ Wab2,
                                              const u16* __restrict__ Wib,
                                              const float* __restrict__ bi,
                                              const float* __restrict__ bias1,
                                              const float* __restrict__ bias2,
                                              float* __restrict__ out0) {
  __shared__ __align__(16) u16 As[128 * 32];
  __shared__ __align__(16) u16 Bs[128 * 32];
  __shared__ __align__(16) u16 Bs2[128 * 32];
  const int tid = threadIdx.x;
  const int r0 = blockIdx.x * 128, c0 = blockIdx.y * 128;
  const int lane = tid & 63, wave = tid >> 6;
  const int wm = wave >> 1, wn = wave & 1;
  const int lm = lane & 15, kq = lane >> 4;

  f32x4 accC[4][4] = {};
  f32x4 accX[4][4] = {};
  for (int k0 = 0; k0 < 512; k0 += 32) {
#pragma unroll
    for (int rr = 0; rr < 2; rr++) {
      int c = tid + rr * 256;
      int row = c >> 2, col = (c & 3) * 8;
      int r = r0 + row;
      size_t src;
      if (k0 < 256) {
        src = (size_t)(r + 1) * NIN + k0 + col;            // IN_t  (INz row r+1)
      } else {
        int pz = ((r & (T_LEN - 1)) == 0) ? 0 : r;         // IN_{t-1} (zero row at t==0)
        src = (size_t)pz * NIN + (k0 - 256) + col;
      }
      gload_lds16(INz + src, (char*)As + c * 16);
      gload_lds16(Wab2 + (size_t)(c0 + row) * 512 + k0 + col, (char*)Bs + c * 16);
      if (k0 < 256)
        gload_lds16(Wib + (size_t)(c0 + row) * NIN + k0 + col, (char*)Bs2 + c * 16);
    }
    __syncthreads();
    bf16x8 a[4], b[4];
#pragma unroll
    for (int i = 0; i < 4; i++) {
      a[i] = *(const bf16x8*)&As[(wm * 64 + i * 16 + lm) * 32 + kq * 8];
      b[i] = *(const bf16x8*)&Bs[(wn * 64 + i * 16 + lm) * 32 + kq * 8];
    }
#pragma unroll
    for (int i = 0; i < 4; i++)
#pragma unroll
      for (int jn = 0; jn < 4; jn++)
        accC[i][jn] = __builtin_amdgcn_mfma_f32_16x16x32_bf16(a[i], b[jn], accC[i][jn], 0, 0, 0);
    if (k0 < 256) {
      bf16x8 b2[4];
#pragma unroll
      for (int i = 0; i < 4; i++)
        b2[i] = *(const bf16x8*)&Bs2[(wn * 64 + i * 16 + lm) * 32 + kq * 8];
#pragma unroll
      for (int i = 0; i < 4; i++)
#pragma unroll
        for (int jn = 0; jn < 4; jn++)
          accX[i][jn] = __builtin_amdgcn_mfma_f32_16x16x32_bf16(a[i], b2[jn], accX[i][jn], 0, 0, 0);
    }
    __syncthreads();
  }
#pragma unroll
  for (int i = 0; i < 4; i++) {
    int grb = r0 + wm * 64 + i * 16 + kq * 4;
#pragma unroll
    for (int jn = 0; jn < 4; jn++) {
      int gc = c0 + wn * 64 + jn * 16 + lm;
      float b1 = bias1[gc], b2v = bias2[gc], biv = bi[gc];
#pragma unroll
      for (int j = 0; j < 4; j++) {
        int gr = grb + j;
        float bb = b1 + (((gr & (T_LEN - 1)) != 0) ? b2v : 0.0f);
        float cv = fmaxf(accC[i][jn][j] + bb, 0.0f);
        float x = accX[i][jn][j] + biv;
        out0[(size_t)gr * NH + gc] = 0.98f * x + 0.02f * cv;
      }
    }
  }
}

// ---------------- GEMM3: OUT = H * Wo^T + bo  (A reg-staged f32->bf16) ----------------
__global__ __launch_bounds__(256) void gemm3(const float* __restrict__ H,
                                             const u16* __restrict__ Wob,
                                             const float* __restrict__ bo,
                                             float* __restrict__ out1) {
  __shared__ __align__(16) u16 As[128 * 32];
  __shared__ __align__(16) u16 Bs[128 * 32];
  const int tid = threadIdx.x;
  const int r0 = blockIdx.x * 128, c0 = blockIdx.y * 128;
  const int lane = tid & 63, wave = tid >> 6;
  const int wm = wave >> 1, wn = wave & 1;
  const int lm = lane & 15, kq = lane >> 4;

  f32x4 acc[4][4] = {};
  for (int k0 = 0; k0 < NH; k0 += 32) {
#pragma unroll
    for (int rr = 0; rr < 2; rr++) {
      int c = tid + rr * 256;
      int row = c >> 2, col = (c & 3) * 8;
      const float* src = H + (size_t)(r0 + row) * NH + k0 + col;
      float4 v0 = *(const float4*)src;
      float4 v1 = *(const float4*)(src + 4);
      union { u16 u[8]; uint4 q; } pk;
      pk.u[0] = f2bf(v0.x); pk.u[1] = f2bf(v0.y); pk.u[2] = f2bf(v0.z); pk.u[3] = f2bf(v0.w);
      pk.u[4] = f2bf(v1.x); pk.u[5] = f2bf(v1.y); pk.u[6] = f2bf(v1.z); pk.u[7] = f2bf(v1.w);
      *(uint4*)((char*)As + c * 16) = pk.q;
      gload_lds16(Wob + (size_t)(c0 + row) * NH + k0 + col, (char*)Bs + c * 16);
    }
    __syncthreads();
    bf16x8 a[4], b[4];
#pragma unroll
    for (int i = 0; i < 4; i++) {
      a[i] = *(const bf16x8*)&As[(wm * 64 + i * 16 + lm) * 32 + kq * 8];
      b[i] = *(const bf16x8*)&Bs[(wn * 64 + i * 16 + lm) * 32 + kq * 8];
    }
#pragma unroll
    for (int i = 0; i < 4; i++)
#pragma unroll
      for (int jn = 0; jn < 4; jn++)
        acc[i][jn] = __builtin_amdgcn_mfma_f32_16x16x32_bf16(a[i], b[jn], acc[i][jn], 0, 0, 0);
    __syncthreads();
  }
#pragma unroll
  for (int i = 0; i < 4; i++) {
    int grb = r0 + wm * 64 + i * 16 + kq * 4;
#pragma unroll
    for (int jn = 0; jn < 4; jn++) {
      int gc = c0 + wn * 64 + jn * 16 + lm;
      float bv = bo[gc];
#pragma unroll
      for (int j = 0; j < 4; j++)
        out1[(size_t)(grb + j) * NOUT + gc] = acc[i][jn][j] + bv;
    }
  }
}

extern "C" void kernel_launch(void* const* d_in, const int* in_sizes, int n_in,
                              void* d_out, int out_size, void* d_ws, size_t ws_size,
                              hipStream_t stream) {
  const float* inp = (const float*)d_in[0];
  const float* Wi  = (const float*)d_in[1];
  const float* bi  = (const float*)d_in[2];
  const float* Wih = (const float*)d_in[3];
  const float* bih = (const float*)d_in[4];
  const float* Whh = (const float*)d_in[5];
  const float* bhh = (const float*)d_in[6];
  const float* Wo  = (const float*)d_in[7];
  const float* bo  = (const float*)d_in[8];

  float* out0 = (float*)d_out;                       // hidden [32768,1024] f32
  float* out1 = out0 + (size_t)M_TOT * NH;           // output [32768,256]  f32

  char* ws = (char*)d_ws;
  u16* Acat = (u16*)ws;                              //  2048 x 1024 bf16 =  4,194,304 B
  u16* WiT  = (u16*)(ws + 4194304);                  //   256 x 1024 bf16 =    524,288 B
  u16* Wab2 = (u16*)(ws + 4718592);                  //  1024 x  512 bf16 =  1,048,576 B
  u16* Wib  = (u16*)(ws + 5767168);                  //  1024 x  256 bf16 =    524,288 B
  u16* Wob  = (u16*)(ws + 6291456);                  //   256 x 1024 bf16 =    524,288 B
  float* bias1 = (float*)(ws + 6815744);             //  1024 f32 = 4096 B
  float* bias2 = (float*)(ws + 6819840);             //  1024 f32 = 4096 B
  // total ws usage: 6,823,936 B (well under the 72 MB proven in round 0)
  // INz lives in the out1 region (33.5 MB >= 16.8 MB); dead before gemm3 writes out1.
  u16* INz = (u16*)out1;                             // [1+32768][256] bf16 = 16,777,728 B

  hipLaunchKernelGGL(prep, dim3(2048), dim3(256), 0, stream,
                     inp, Wi, Wih, Whh, Wo, INz, WiT, Acat, Wib, Wob);
  hipLaunchKernelGGL(wab, dim3(16, 2), dim3(256), 0, stream, Acat, WiT, Wab2);
  hipLaunchKernelGGL(biasvec, dim3(1024), dim3(256), 0, stream,
                     Wih, Whh, bi, bih, bhh, bias1, bias2);
  hipLaunchKernelGGL(fused2, dim3(256, 8), dim3(256), 0, stream,
                     INz, Wab2, Wib, bi, bias1, bias2, out0);
  hipLaunchKernelGGL(gemm3, dim3(256, 2), dim3(256), 0, stream, out0, Wob, bo, out1);
}

// Round 4
// 158.608 us; speedup vs baseline: 1.2426x; 1.2426x over previous
//
#include <hip/hip_runtime.h>

#define M_TOT 32768   // B*T = 64*512
#define T_LEN 512
#define NIN   256
#define NH    1024
#define NOUT  256

typedef __attribute__((ext_vector_type(8))) short bf16x8;
typedef __attribute__((ext_vector_type(4))) float f32x4;
typedef unsigned short u16;

__device__ inline float bf2f(u16 u) {
  union { float f; unsigned int i; } v; v.i = ((unsigned int)u) << 16; return v.f;
}
__device__ inline u16 f2bf(float f) {
  union { float f; unsigned int i; } v; v.f = f;
  unsigned int r = v.i + 0x7FFFu + ((v.i >> 16) & 1u);
  return (u16)(r >> 16);
}

__device__ inline void gload_lds16(const void* g, void* l) {
  __builtin_amdgcn_global_load_lds(
      (const __attribute__((address_space(1))) void*)g,
      (__attribute__((address_space(3))) void*)l, 16, 0, 0);
}

// ---------------- prep: bf16 conversions, WiT transpose, Acat build, zero row ----------------
// INz layout: row 0 = zeros (256), row r>=1 = IN row r-1.  [32769][256] bf16
__global__ void prep(const float* __restrict__ inp, const float* __restrict__ Wi,
                     const float* __restrict__ Wih, const float* __restrict__ Whh,
                     const float* __restrict__ Wo,
                     u16* __restrict__ INz, u16* __restrict__ WiT,
                     u16* __restrict__ Acat, u16* __restrict__ Wib, u16* __restrict__ Wob) {
  const long nINz = 256L + (long)M_TOT * NIN;   // 8,388,864
  const long nWiT = 256L * NH;                  // 262,144
  const long nAc  = 2048L * NH;                 // 2,097,152
  const long nWi  = (long)NH * NIN;             // 262,144
  const long nWo  = (long)NOUT * NH;            // 262,144
  const long total = nINz + nWiT + nAc + nWi + nWo;
  for (long i = (long)blockIdx.x * blockDim.x + threadIdx.x; i < total;
       i += (long)gridDim.x * blockDim.x) {
    long j = i;
    if (j < nINz) { INz[j] = (j < 256) ? (u16)0 : f2bf(inp[j - 256]); continue; }
    j -= nINz;
    if (j < nWiT) {  // WiT[it][h] = Wi[h][it]
      long it = j >> 10, h = j & 1023;
      WiT[j] = f2bf(Wi[h * NIN + it]);
      continue;
    }
    j -= nWiT;
    if (j < nAc) {   // Acat = [W_ih ; 0.98*W_hh]  (2048 x 1024)
      long g = j >> 10, h = j & 1023;
      Acat[j] = (g < NH) ? f2bf(Wih[g * NH + h])
                         : f2bf(0.98f * Whh[(g - NH) * NH + h]);
      continue;
    }
    j -= nAc;
    if (j < nWi) { Wib[j] = f2bf(Wi[j]); continue; }
    j -= nWi;
    Wob[j] = f2bf(Wo[j]);
  }
}

// ---------------- biasvec: b1[g]=bih+bhh+W_ih.bi ; b2[g]=0.98*W_hh.bi ----------------
__global__ __launch_bounds__(256) void biasvec(const float* __restrict__ Wih,
                                               const float* __restrict__ Whh,
                                               const float* __restrict__ bi,
                                               const float* __restrict__ bih,
                                               const float* __restrict__ bhh,
                                               float* __restrict__ bias1,
                                               float* __restrict__ bias2) {
  __shared__ float s1[256], s2[256];
  const int g = blockIdx.x, tid = threadIdx.x;
  float a1 = 0.f, a2 = 0.f;
#pragma unroll
  for (int q = 0; q < 4; q++) {
    int h = tid + q * 256;
    float bv = bi[h];
    a1 += Wih[(size_t)g * NH + h] * bv;
    a2 += Whh[(size_t)g * NH + h] * bv;
  }
  s1[tid] = a1; s2[tid] = a2;
  __syncthreads();
  for (int off = 128; off > 0; off >>= 1) {
    if (tid < off) { s1[tid] += s1[tid + off]; s2[tid] += s2[tid + off]; }
    __syncthreads();
  }
  if (tid == 0) {
    bias1[g] = s1[0] + bih[g] + bhh[g];
    bias2[g] = 0.98f * s2[0];
  }
}

// ---------------- wab: Wab2 = [Wa | Wb] folded weights, M=2048,N=256,K=1024 ----------------
__global__ __launch_bounds__(256) void wab(const u16* __restrict__ Acat,
                                           const u16* __restrict__ WiT,
                                           u16* __restrict__ Wab2) {
  __shared__ __align__(16) u16 As[128 * 32];
  __shared__ __align__(16) u16 Bs[128 * 32];
  const int tid = threadIdx.x;
  const int r0 = blockIdx.x * 128, c0 = blockIdx.y * 128;
  const int lane = tid & 63, wave = tid >> 6;
  const int wm = wave >> 1, wn = wave & 1;
  const int lm = lane & 15, kq = lane >> 4;

  f32x4 acc[4][4] = {};
  for (int k0 = 0; k0 < NH; k0 += 32) {
#pragma unroll
    for (int rr = 0; rr < 2; rr++) {
      int c = tid + rr * 256;
      int row = c >> 2, col = (c & 3) * 8;
      gload_lds16(Acat + (size_t)(r0 + row) * NH + k0 + col, (char*)As + c * 16);
      gload_lds16(WiT + (size_t)(c0 + row) * NH + k0 + col, (char*)Bs + c * 16);
    }
    __syncthreads();
    bf16x8 a[4], b[4];
#pragma unroll
    for (int i = 0; i < 4; i++) {
      a[i] = *(const bf16x8*)&As[(wm * 64 + i * 16 + lm) * 32 + kq * 8];
      b[i] = *(const bf16x8*)&Bs[(wn * 64 + i * 16 + lm) * 32 + kq * 8];
    }
#pragma unroll
    for (int i = 0; i < 4; i++)
#pragma unroll
      for (int jn = 0; jn < 4; jn++)
        acc[i][jn] = __builtin_amdgcn_mfma_f32_16x16x32_bf16(a[i], b[jn], acc[i][jn], 0, 0, 0);
    __syncthreads();
  }
#pragma unroll
  for (int i = 0; i < 4; i++) {
    int grb = r0 + wm * 64 + i * 16 + kq * 4;
#pragma unroll
    for (int jn = 0; jn < 4; jn++) {
      int gc = c0 + wn * 64 + jn * 16 + lm;
#pragma unroll
      for (int j = 0; j < 4; j++) {
        int g = grb + j;
        size_t dst = (g < NH) ? ((size_t)g * 512 + gc)
                              : ((size_t)(g - NH) * 512 + 256 + gc);
        Wab2[dst] = f2bf(acc[i][jn][j]);
      }
    }
  }
}

// ---- fused2 v2: single-barrier double-buffered pipeline ----
// accX = IN_t*Wi^T (K=256); accC = IN_t*Wa^T + IN_prev*Wb^T (K=512);
// H = 0.98*(accX+bi) + 0.02*relu(accC + b1 [+ b2 if t!=0]) -> out0 f32
__global__ __launch_bounds__(256) void fused2(const u16* __restrict__ INz,
                                              const u16* __restrict__ Wab2,
                                              const u16* __restrict__ Wib,
                                              const float* __restrict__ bi,
                                              const float* __restrict__ bias1,
                                              const float* __restrict__ bias2,
                                              float* __restrict__ out0) {
  __shared__ __align__(16) u16 As[2][128 * 32];
  __shared__ __align__(16) u16 Bs[2][128 * 32];
  __shared__ __align__(16) u16 Bs2[2][128 * 32];
  const int tid = threadIdx.x;
  const int r0 = blockIdx.x * 128, c0 = blockIdx.y * 128;
  const int lane = tid & 63, wave = tid >> 6;
  const int wm = wave >> 1, wn = wave & 1;
  const int lm = lane & 15, kq = lane >> 4;

  // staging address pieces (constant across iters)
  const int c1 = tid, c2 = tid + 256;
  const int row1 = c1 >> 2, col1 = (c1 & 3) * 8;
  const int row2 = c2 >> 2, col2 = (c2 & 3) * 8;
  const int ra1 = r0 + row1, ra2 = r0 + row2;
  const int pz1 = ((ra1 & (T_LEN - 1)) == 0) ? 0 : ra1;
  const int pz2 = ((ra2 & (T_LEN - 1)) == 0) ? 0 : ra2;

#define STAGE_AB1(buf, k0)                                                        \
  {                                                                               \
    gload_lds16(INz + (size_t)(ra1 + 1) * NIN + (k0) + col1,                      \
                (char*)As[buf] + c1 * 16);                                        \
    gload_lds16(INz + (size_t)(ra2 + 1) * NIN + (k0) + col2,                      \
                (char*)As[buf] + c2 * 16);                                        \
    gload_lds16(Wab2 + (size_t)(c0 + row1) * 512 + (k0) + col1,                   \
                (char*)Bs[buf] + c1 * 16);                                        \
    gload_lds16(Wab2 + (size_t)(c0 + row2) * 512 + (k0) + col2,                   \
                (char*)Bs[buf] + c2 * 16);                                        \
  }
#define STAGE_AB2(buf, k0)                                                        \
  {                                                                               \
    gload_lds16(INz + (size_t)pz1 * NIN + ((k0) - 256) + col1,                    \
                (char*)As[buf] + c1 * 16);                                        \
    gload_lds16(INz + (size_t)pz2 * NIN + ((k0) - 256) + col2,                    \
                (char*)As[buf] + c2 * 16);                                        \
    gload_lds16(Wab2 + (size_t)(c0 + row1) * 512 + (k0) + col1,                   \
                (char*)Bs[buf] + c1 * 16);                                        \
    gload_lds16(Wab2 + (size_t)(c0 + row2) * 512 + (k0) + col2,                   \
                (char*)Bs[buf] + c2 * 16);                                        \
  }
#define STAGE_B2(buf, k0)                                                         \
  {                                                                               \
    gload_lds16(Wib + (size_t)(c0 + row1) * NIN + (k0) + col1,                    \
                (char*)Bs2[buf] + c1 * 16);                                       \
    gload_lds16(Wib + (size_t)(c0 + row2) * NIN + (k0) + col2,                    \
                (char*)Bs2[buf] + c2 * 16);                                       \
  }

  f32x4 accC[4][4] = {};
  f32x4 accX[4][4] = {};

  // prologue: stage tile 0
  STAGE_AB1(0, 0);
  STAGE_B2(0, 0);
  __syncthreads();

  int cur = 0;
  // ---- phase 1: k0 = 0..224, both GEMMs ----
  for (int it = 0; it < 8; ++it) {
    const int k0n = (it + 1) * 32;
    if (it < 7) {
      STAGE_AB1(cur ^ 1, k0n);
      STAGE_B2(cur ^ 1, k0n);
    } else {
      STAGE_AB2(cur ^ 1, k0n);  // first phase-2 tile (k0n == 256), no B2
    }
    bf16x8 a[4], b[4], b2[4];
#pragma unroll
    for (int i = 0; i < 4; i++) {
      a[i]  = *(const bf16x8*)&As[cur][(wm * 64 + i * 16 + lm) * 32 + kq * 8];
      b[i]  = *(const bf16x8*)&Bs[cur][(wn * 64 + i * 16 + lm) * 32 + kq * 8];
      b2[i] = *(const bf16x8*)&Bs2[cur][(wn * 64 + i * 16 + lm) * 32 + kq * 8];
    }
#pragma unroll
    for (int i = 0; i < 4; i++)
#pragma unroll
      for (int jn = 0; jn < 4; jn++) {
        accC[i][jn] = __builtin_amdgcn_mfma_f32_16x16x32_bf16(a[i], b[jn], accC[i][jn], 0, 0, 0);
        accX[i][jn] = __builtin_amdgcn_mfma_f32_16x16x32_bf16(a[i], b2[jn], accX[i][jn], 0, 0, 0);
      }
    __syncthreads();
    cur ^= 1;
  }
  // ---- phase 2: k0 = 256..480, accC only ----
  for (int it = 8; it < 16; ++it) {
    if (it < 15) {
      const int k0n = (it + 1) * 32;
      STAGE_AB2(cur ^ 1, k0n);
    }
    bf16x8 a[4], b[4];
#pragma unroll
    for (int i = 0; i < 4; i++) {
      a[i] = *(const bf16x8*)&As[cur][(wm * 64 + i * 16 + lm) * 32 + kq * 8];
      b[i] = *(const bf16x8*)&Bs[cur][(wn * 64 + i * 16 + lm) * 32 + kq * 8];
    }
#pragma unroll
    for (int i = 0; i < 4; i++)
#pragma unroll
      for (int jn = 0; jn < 4; jn++)
        accC[i][jn] = __builtin_amdgcn_mfma_f32_16x16x32_bf16(a[i], b[jn], accC[i][jn], 0, 0, 0);
    __syncthreads();
    cur ^= 1;
  }
#undef STAGE_AB1
#undef STAGE_AB2
#undef STAGE_B2

#pragma unroll
  for (int i = 0; i < 4; i++) {
    int grb = r0 + wm * 64 + i * 16 + kq * 4;
#pragma unroll
    for (int jn = 0; jn < 4; jn++) {
      int gc = c0 + wn * 64 + jn * 16 + lm;
      float b1 = bias1[gc], b2v = bias2[gc], biv = bi[gc];
#pragma unroll
      for (int j = 0; j < 4; j++) {
        int gr = grb + j;
        float bb = b1 + (((gr & (T_LEN - 1)) != 0) ? b2v : 0.0f);
        float cv = fmaxf(accC[i][jn][j] + bb, 0.0f);
        float x = accX[i][jn][j] + biv;
        out0[(size_t)gr * NH + gc] = 0.98f * x + 0.02f * cv;
      }
    }
  }
}

// ---------------- GEMM3: OUT = H * Wo^T + bo  (A reg-staged f32->bf16) ----------------
__global__ __launch_bounds__(256) void gemm3(const float* __restrict__ H,
                                             const u16* __restrict__ Wob,
                                             const float* __restrict__ bo,
                                             float* __restrict__ out1) {
  __shared__ __align__(16) u16 As[128 * 32];
  __shared__ __align__(16) u16 Bs[128 * 32];
  const int tid = threadIdx.x;
  const int r0 = blockIdx.x * 128, c0 = blockIdx.y * 128;
  const int lane = tid & 63, wave = tid >> 6;
  const int wm = wave >> 1, wn = wave & 1;
  const int lm = lane & 15, kq = lane >> 4;

  f32x4 acc[4][4] = {};
  for (int k0 = 0; k0 < NH; k0 += 32) {
#pragma unroll
    for (int rr = 0; rr < 2; rr++) {
      int c = tid + rr * 256;
      int row = c >> 2, col = (c & 3) * 8;
      const float* src = H + (size_t)(r0 + row) * NH + k0 + col;
      float4 v0 = *(const float4*)src;
      float4 v1 = *(const float4*)(src + 4);
      union { u16 u[8]; uint4 q; } pk;
      pk.u[0] = f2bf(v0.x); pk.u[1] = f2bf(v0.y); pk.u[2] = f2bf(v0.z); pk.u[3] = f2bf(v0.w);
      pk.u[4] = f2bf(v1.x); pk.u[5] = f2bf(v1.y); pk.u[6] = f2bf(v1.z); pk.u[7] = f2bf(v1.w);
      *(uint4*)((char*)As + c * 16) = pk.q;
      gload_lds16(Wob + (size_t)(c0 + row) * NH + k0 + col, (char*)Bs + c * 16);
    }
    __syncthreads();
    bf16x8 a[4], b[4];
#pragma unroll
    for (int i = 0; i < 4; i++) {
      a[i] = *(const bf16x8*)&As[(wm * 64 + i * 16 + lm) * 32 + kq * 8];
      b[i] = *(const bf16x8*)&Bs[(wn * 64 + i * 16 + lm) * 32 + kq * 8];
    }
#pragma unroll
    for (int i = 0; i < 4; i++)
#pragma unroll
      for (int jn = 0; jn < 4; jn++)
        acc[i][jn] = __builtin_amdgcn_mfma_f32_16x16x32_bf16(a[i], b[jn], acc[i][jn], 0, 0, 0);
    __syncthreads();
  }
#pragma unroll
  for (int i = 0; i < 4; i++) {
    int grb = r0 + wm * 64 + i * 16 + kq * 4;
#pragma unroll
    for (int jn = 0; jn < 4; jn++) {
      int gc = c0 + wn * 64 + jn * 16 + lm;
      float bv = bo[gc];
#pragma unroll
      for (int j = 0; j < 4; j++)
        out1[(size_t)(grb + j) * NOUT + gc] = acc[i][jn][j] + bv;
    }
  }
}

extern "C" void kernel_launch(void* const* d_in, const int* in_sizes, int n_in,
                              void* d_out, int out_size, void* d_ws, size_t ws_size,
                              hipStream_t stream) {
  const float* inp = (const float*)d_in[0];
  const float* Wi  = (const float*)d_in[1];
  const float* bi  = (const float*)d_in[2];
  const float* Wih = (const float*)d_in[3];
  const float* bih = (const float*)d_in[4];
  const float* Whh = (const float*)d_in[5];
  const float* bhh = (const float*)d_in[6];
  const float* Wo  = (const float*)d_in[7];
  const float* bo  = (const float*)d_in[8];

  float* out0 = (float*)d_out;                       // hidden [32768,1024] f32
  float* out1 = out0 + (size_t)M_TOT * NH;           // output [32768,256]  f32

  char* ws = (char*)d_ws;
  u16* Acat = (u16*)ws;                              //  2048 x 1024 bf16 =  4,194,304 B
  u16* WiT  = (u16*)(ws + 4194304);                  //   256 x 1024 bf16 =    524,288 B
  u16* Wab2 = (u16*)(ws + 4718592);                  //  1024 x  512 bf16 =  1,048,576 B
  u16* Wib  = (u16*)(ws + 5767168);                  //  1024 x  256 bf16 =    524,288 B
  u16* Wob  = (u16*)(ws + 6291456);                  //   256 x 1024 bf16 =    524,288 B
  float* bias1 = (float*)(ws + 6815744);             //  1024 f32 = 4096 B
  float* bias2 = (float*)(ws + 6819840);             //  1024 f32 = 4096 B
  // total ws usage: 6,823,936 B
  // INz lives in the out1 region (33.5 MB >= 16.8 MB); dead before gemm3 writes out1.
  u16* INz = (u16*)out1;                             // [1+32768][256] bf16 = 16,777,728 B

  hipLaunchKernelGGL(prep, dim3(2048), dim3(256), 0, stream,
                     inp, Wi, Wih, Whh, Wo, INz, WiT, Acat, Wib, Wob);
  hipLaunchKernelGGL(wab, dim3(16, 2), dim3(256), 0, stream, Acat, WiT, Wab2);
  hipLaunchKernelGGL(biasvec, dim3(1024), dim3(256), 0, stream,
                     Wih, Whh, bi, bih, bhh, bias1, bias2);
  hipLaunchKernelGGL(fused2, dim3(256, 8), dim3(256), 0, stream,
                     INz, Wab2, Wib, bi, bias1, bias2, out0);
  hipLaunchKernelGGL(gemm3, dim3(256, 2), dim3(256), 0, stream, out0, Wob, bo, out1);
}